// Round 1
// baseline (25010.263 us; speedup 1.0000x reference)
//
#include <hip/hip_runtime.h>
#include <math.h>

// Problem constants
#define S_ 64
#define B_ 32
#define T_ 64
#define E_ 512
#define H_ 1024
#define G_ 3072   // 3*H
#define V_ 32000

__device__ __forceinline__ float sigmoidf_(float x) { return 1.f / (1.f + expf(-x)); }

// ---------------- utility kernels ----------------
__global__ void zero_k(float* __restrict__ p, int n) {
  int i = blockIdx.x * blockDim.x + threadIdx.x;
  if (i < n) p[i] = 0.f;
}

__global__ void build_dec_idx_k(const int* __restrict__ tgt, int* __restrict__ idx) {
  int t = blockIdx.x, b = threadIdx.x;  // grid 64, block 32
  idx[t * B_ + b] = (t == 0) ? 2 : tgt[(t - 1) * B_ + b];
}

// ---------------- generic tiled fp32 GEMM: C = gather(A) @ W (+ bias) ----------------
// Tile 64x64, K-tile 16, 256 threads, 4x4 per thread. All dims divisible (M=2048,
// N in {1024,3072,32000}, K in {512,1024}) so no bounds checks.
template <bool GATHER, bool BIAS>
__global__ __launch_bounds__(256) void gemm_k(
    const float* __restrict__ A, const int* __restrict__ idx,
    const float* __restrict__ W, const float* __restrict__ bias,
    float* __restrict__ C, int M, int N, int K)
{
  __shared__ float As[16][64];
  __shared__ float Bs[16][64];
  const int n0 = blockIdx.x * 64;
  const int m0 = blockIdx.y * 64;
  const int tid = threadIdx.x;
  const int tx = tid & 15, ty = tid >> 4;
  float acc[4][4] = {};
  for (int k0 = 0; k0 < K; k0 += 16) {
    #pragma unroll
    for (int t = tid; t < 1024; t += 256) {
      int mm = t >> 4, kk = t & 15;
      int m = m0 + mm;
      const float* row = GATHER ? (A + (size_t)idx[m] * K) : (A + (size_t)m * K);
      As[kk][mm] = row[k0 + kk];
    }
    #pragma unroll
    for (int t = tid; t < 1024; t += 256) {
      int kk = t >> 6, nn = t & 63;
      Bs[kk][nn] = W[(size_t)(k0 + kk) * N + (n0 + nn)];
    }
    __syncthreads();
    #pragma unroll
    for (int kk = 0; kk < 16; ++kk) {
      float a[4], b[4];
      *(float4*)a = *(const float4*)&As[kk][ty * 4];
      *(float4*)b = *(const float4*)&Bs[kk][tx * 4];
      #pragma unroll
      for (int i = 0; i < 4; ++i)
        #pragma unroll
        for (int j = 0; j < 4; ++j)
          acc[i][j] = fmaf(a[i], b[j], acc[i][j]);
    }
    __syncthreads();
  }
  #pragma unroll
  for (int i = 0; i < 4; ++i) {
    int m = m0 + ty * 4 + i;
    float* crow = C + (size_t)m * N + n0;
    #pragma unroll
    for (int j = 0; j < 4; ++j) {
      int n = tx * 4 + j;
      crow[n] = acc[i][j] + (BIAS ? bias[n0 + n] : 0.f);
    }
  }
}

// ---------------- encoder GRU step ----------------
// One thread per (b,i): computes all 3 gate dot-products so the whole GRU update
// fuses in one kernel. Block = 4 b-rows (one per wave) x 64 i. Grid (16, 8).
// Reads h from h_prev slice, writes h2 to h_out slice (no cross-block race).
__global__ __launch_bounds__(256) void enc_step_k(
    const float* __restrict__ Wh, const float* __restrict__ bh,
    const float* __restrict__ gx,      // (B, 3H) for this s
    const float* __restrict__ h_prev,  // (B, H)
    float* __restrict__ h_out)         // (B, H) -> enc_outs slice
{
  __shared__ float hs[4][H_];
  const int il = threadIdx.x & 63;
  const int wv = threadIdx.x >> 6;  // local b
  const int i = blockIdx.x * 64 + il;
  const int b = blockIdx.y * 4 + wv;
  for (int t = threadIdx.x; t < 4 * H_; t += 256)
    hs[t >> 10][t & (H_ - 1)] = h_prev[(blockIdx.y * 4 + (t >> 10)) * H_ + (t & (H_ - 1))];
  __syncthreads();
  float ar = 0.f, az = 0.f, an = 0.f;
  const float* w = Wh + i;
  #pragma unroll 8
  for (int k = 0; k < H_; ++k) {
    float hv = hs[wv][k];
    const float* wk = w + (size_t)k * G_;
    ar = fmaf(hv, wk[0], ar);
    az = fmaf(hv, wk[H_], az);
    an = fmaf(hv, wk[2 * H_], an);
  }
  const float* gxb = gx + b * G_;
  float r = sigmoidf_(gxb[i] + ar + bh[i]);
  float z = sigmoidf_(gxb[H_ + i] + az + bh[H_ + i]);
  float n = tanhf(gxb[2 * H_ + i] + r * (an + bh[2 * H_ + i]));
  h_out[b * H_ + i] = (1.f - z) * n + z * hs[wv][i];
}

// ---------------- decoder attention: pre = h @ W1 ----------------
__global__ __launch_bounds__(256) void attn_pre_k(
    const float* __restrict__ W1,      // attn_W[:H] (H,H)
    const float* __restrict__ h_prev,  // (B,H)
    float* __restrict__ pre)           // (B,H)
{
  __shared__ float hs[4][H_];
  const int il = threadIdx.x & 63;
  const int wv = threadIdx.x >> 6;
  const int i = blockIdx.x * 64 + il;
  const int b = blockIdx.y * 4 + wv;
  for (int t = threadIdx.x; t < 4 * H_; t += 256)
    hs[t >> 10][t & (H_ - 1)] = h_prev[(blockIdx.y * 4 + (t >> 10)) * H_ + (t & (H_ - 1))];
  __syncthreads();
  float acc = 0.f;
  const float* w = W1 + i;
  #pragma unroll 8
  for (int k = 0; k < H_; ++k)
    acc = fmaf(hs[wv][k], w[(size_t)k * H_], acc);
  pre[b * H_ + i] = acc;
}

// ---------------- decoder attention: scores -> softmax -> ctx, one block per b ----------------
__global__ __launch_bounds__(256) void attn_ctx_k(
    const float* __restrict__ pre,       // (B,H)
    const float* __restrict__ enc_proj,  // (S,B,H)
    const float* __restrict__ v,         // (H)
    const float* __restrict__ enc_outs,  // (S,B,H)
    float* __restrict__ ctx)             // (B,H)
{
  const int b = blockIdx.x;
  __shared__ float pre_s[H_];
  __shared__ float v_s[H_];
  __shared__ float aw[S_];
  for (int t = threadIdx.x; t < H_; t += 256) { pre_s[t] = pre[b * H_ + t]; v_s[t] = v[t]; }
  __syncthreads();
  const int lane = threadIdx.x & 63;
  const int wv = threadIdx.x >> 6;
  for (int s = wv; s < S_; s += 4) {
    const float* ep = enc_proj + ((size_t)s * B_ + b) * H_;
    float acc = 0.f;
    for (int k = lane; k < H_; k += 64)
      acc += tanhf(pre_s[k] + ep[k]) * v_s[k];
    #pragma unroll
    for (int off = 32; off; off >>= 1) acc += __shfl_down(acc, off);
    if (lane == 0) aw[s] = acc;
  }
  __syncthreads();
  if (threadIdx.x < S_) {   // S_==64: exactly wave 0
    float x = aw[threadIdx.x];
    float m = x;
    #pragma unroll
    for (int off = 32; off; off >>= 1) m = fmaxf(m, __shfl_xor(m, off));
    float e = expf(x - m);
    float sum = e;
    #pragma unroll
    for (int off = 32; off; off >>= 1) sum += __shfl_xor(sum, off);
    aw[threadIdx.x] = e / sum;
  }
  __syncthreads();
  for (int h0 = threadIdx.x; h0 < H_; h0 += 256) {
    float acc = 0.f;
    #pragma unroll 8
    for (int s = 0; s < S_; ++s)
      acc = fmaf(aw[s], enc_outs[((size_t)s * B_ + b) * H_ + h0], acc);
    ctx[b * H_ + h0] = acc;
  }
}

// ---------------- decoder GRU step (h@Wh_d + ctx@Wc_d fused) ----------------
__global__ __launch_bounds__(256) void dec_step_k(
    const float* __restrict__ Wh, const float* __restrict__ Wc,
    const float* __restrict__ bh,
    const float* __restrict__ gx,      // (B,3H) for this t
    const float* __restrict__ ctx,     // (B,H)
    const float* __restrict__ h_prev,  // (B,H)
    float* __restrict__ h_out)         // (B,H) -> dec_h slice
{
  __shared__ float hs[4][H_];
  __shared__ float cs[4][H_];
  const int il = threadIdx.x & 63;
  const int wv = threadIdx.x >> 6;
  const int i = blockIdx.x * 64 + il;
  const int b = blockIdx.y * 4 + wv;
  for (int t = threadIdx.x; t < 4 * H_; t += 256) {
    int rb = t >> 10, rk = t & (H_ - 1);
    hs[rb][rk] = h_prev[(blockIdx.y * 4 + rb) * H_ + rk];
    cs[rb][rk] = ctx[(blockIdx.y * 4 + rb) * H_ + rk];
  }
  __syncthreads();
  float ar = 0.f, az = 0.f, an = 0.f, cr = 0.f, cz = 0.f, cn = 0.f;
  const float* wh = Wh + i;
  const float* wc = Wc + i;
  #pragma unroll 4
  for (int k = 0; k < H_; ++k) {
    float hv = hs[wv][k], cv = cs[wv][k];
    const float* whk = wh + (size_t)k * G_;
    const float* wck = wc + (size_t)k * G_;
    ar = fmaf(hv, whk[0], ar);
    az = fmaf(hv, whk[H_], az);
    an = fmaf(hv, whk[2 * H_], an);
    cr = fmaf(cv, wck[0], cr);
    cz = fmaf(cv, wck[H_], cz);
    cn = fmaf(cv, wck[2 * H_], cn);
  }
  const float* gxb = gx + b * G_;
  float r = sigmoidf_(gxb[i] + ar + bh[i] + cr);
  float z = sigmoidf_(gxb[H_ + i] + az + bh[H_ + i] + cz);
  float n = tanhf(gxb[2 * H_ + i] + cn + r * (an + bh[2 * H_ + i]));
  h_out[b * H_ + i] = (1.f - z) * n + z * hs[wv][i];
}

// ---------------- log-softmax in place over rows of V ----------------
__global__ __launch_bounds__(256) void logsoftmax_k(float* __restrict__ out) {
  const int row = blockIdx.x;  // 2048 rows
  float* x = out + (size_t)row * V_;
  __shared__ float red[256];
  float m = -INFINITY;
  for (int v = threadIdx.x; v < V_; v += 256) m = fmaxf(m, x[v]);
  red[threadIdx.x] = m;
  __syncthreads();
  for (int s2 = 128; s2; s2 >>= 1) {
    if (threadIdx.x < s2) red[threadIdx.x] = fmaxf(red[threadIdx.x], red[threadIdx.x + s2]);
    __syncthreads();
  }
  m = red[0];
  __syncthreads();
  float sum = 0.f;
  for (int v = threadIdx.x; v < V_; v += 256) sum += expf(x[v] - m);
  red[threadIdx.x] = sum;
  __syncthreads();
  for (int s2 = 128; s2; s2 >>= 1) {
    if (threadIdx.x < s2) red[threadIdx.x] += red[threadIdx.x + s2];
    __syncthreads();
  }
  float lse = m + logf(red[0]);
  for (int v = threadIdx.x; v < V_; v += 256) x[v] -= lse;
}

extern "C" void kernel_launch(void* const* d_in, const int* in_sizes, int n_in,
                              void* d_out, int out_size, void* d_ws, size_t ws_size,
                              hipStream_t stream)
{
  const int*   src     = (const int*)  d_in[0];
  const int*   tgt     = (const int*)  d_in[1];
  const float* emb_enc = (const float*)d_in[2];
  const float* Wx_e    = (const float*)d_in[3];
  const float* Wh_e    = (const float*)d_in[4];
  const float* bx_e    = (const float*)d_in[5];
  const float* bh_e    = (const float*)d_in[6];
  const float* emb_dec = (const float*)d_in[7];
  const float* Wx_d    = (const float*)d_in[8];
  const float* Wh_d    = (const float*)d_in[9];
  const float* Wc_d    = (const float*)d_in[10];
  const float* bx_d    = (const float*)d_in[11];
  const float* bh_d    = (const float*)d_in[12];
  const float* attn_W  = (const float*)d_in[13];
  const float* attn_v  = (const float*)d_in[14];
  const float* Wout    = (const float*)d_in[15];
  const float* bout    = (const float*)d_in[16];
  float* out = (float*)d_out;

  // Workspace layout (~75.6 MB of fp32)
  float* ws       = (float*)d_ws;
  float* gx_enc   = ws;                          // 2048*3072
  float* gx_dec   = gx_enc  + 2048 * G_;         // 2048*3072
  float* enc_outs = gx_dec  + 2048 * G_;         // 64*32*1024 (also holds h per step)
  float* enc_proj = enc_outs + 2048 * H_;        // 2048*1024
  float* dec_h    = enc_proj + 2048 * H_;        // 2048*1024
  float* h0       = dec_h   + 2048 * H_;         // 32*1024 (zeros)
  float* pre      = h0      + B_ * H_;           // 32*1024
  float* ctx      = pre     + B_ * H_;           // 32*1024
  int*   dec_idx  = (int*)(ctx + B_ * H_);       // 2048 ints

  // h0 = zeros (ws is poisoned 0xAA before every call)
  zero_k<<<dim3(32), dim3(1024), 0, stream>>>(h0, B_ * H_);
  // decoder input ids: [SOS; tgt[:-1]]
  build_dec_idx_k<<<dim3(T_), dim3(B_), 0, stream>>>(tgt, dec_idx);

  // gx_enc = emb_enc[src] @ Wx_e + bx_e   (M=2048, N=3072, K=512)
  gemm_k<true, true><<<dim3(G_ / 64, 2048 / 64), 256, 0, stream>>>(
      emb_enc, src, Wx_e, bx_e, gx_enc, 2048, G_, E_);
  // gx_dec = emb_dec[dec_idx] @ Wx_d + bx_d
  gemm_k<true, true><<<dim3(G_ / 64, 2048 / 64), 256, 0, stream>>>(
      emb_dec, dec_idx, Wx_d, bx_d, gx_dec, 2048, G_, E_);

  // ---- encoder scan ----
  for (int s = 0; s < S_; ++s) {
    const float* hp = (s == 0) ? h0 : (enc_outs + (size_t)(s - 1) * B_ * H_);
    enc_step_k<<<dim3(H_ / 64, B_ / 4), 256, 0, stream>>>(
        Wh_e, bh_e, gx_enc + (size_t)s * B_ * G_, hp, enc_outs + (size_t)s * B_ * H_);
  }

  // enc_proj = enc_outs @ W2  (W2 = attn_W[H:], M=2048, N=1024, K=1024)
  gemm_k<false, false><<<dim3(H_ / 64, 2048 / 64), 256, 0, stream>>>(
      enc_outs, nullptr, attn_W + (size_t)H_ * H_, nullptr, enc_proj, 2048, H_, H_);

  // ---- decoder scan ----
  for (int t = 0; t < T_; ++t) {
    const float* hp = (t == 0) ? (enc_outs + (size_t)(S_ - 1) * B_ * H_)
                               : (dec_h + (size_t)(t - 1) * B_ * H_);
    attn_pre_k<<<dim3(H_ / 64, B_ / 4), 256, 0, stream>>>(attn_W, hp, pre);
    attn_ctx_k<<<dim3(B_), 256, 0, stream>>>(pre, enc_proj, attn_v, enc_outs, ctx);
    dec_step_k<<<dim3(H_ / 64, B_ / 4), 256, 0, stream>>>(
        Wh_d, Wc_d, bh_d, gx_dec + (size_t)t * B_ * G_, ctx, hp,
        dec_h + (size_t)t * B_ * H_);
  }

  // logits = dec_h @ Wout + bout -> straight into d_out (layout m = t*B+b matches (T,B,V))
  gemm_k<false, true><<<dim3(V_ / 64, 2048 / 64), 256, 0, stream>>>(
      dec_h, nullptr, Wout, bout, out, 2048, V_, H_);
  // log-softmax in place
  logsoftmax_k<<<dim3(2048), 256, 0, stream>>>(out);
}